// Round 5
// baseline (459.846 us; speedup 1.0000x reference)
//
#include <hip/hip_runtime.h>
#include <hip/hip_cooperative_groups.h>
#include <hip/hip_bf16.h>
#include <math.h>

namespace cg = cooperative_groups;

#define N_TOKENS 8192
#define DIM      512
#define N_TOOLS  50
#define PARAM_DIM 256
#define N_ROWBLK (N_TOKENS / 64)   // 128
#define TM 128                     // adapted M-tile
#define MAXB 192                   // max batch slots
#define LDSS 72                    // LDS inner stride in bf16 elems (144 B)
#define TILE_SH (64 * LDSS)        // shorts per 64-row tile buffer
#define GRID 512
#define NHEAD 640                  // 128 rowblocks x 5 tiles

#define CVT_XB  4096
#define CVT_PWB 128
#define CVT_RWB 32
#define CVT_UNITS (CVT_XB + CVT_PWB + CVT_RWB + 1)

typedef float  f32x4 __attribute__((ext_vector_type(4)));
typedef short  s16x8 __attribute__((ext_vector_type(8)));
typedef short  s16x4 __attribute__((ext_vector_type(4)));

// ---- workspace layout (ints) ----
#define WS_IDX     0          // 8192
#define WS_COUNTS  8192       // 64
#define WS_CURSOR  8256       // 64
#define WS_OFFSETS 8320       // 64
#define WS_BE      8384       // 192
#define WS_BM0     8576       // 192
#define WS_NB      8768       // 16
#define WS_ORDER   8784       // 8192
#define WS_PWH     16976      // 256*512 bf16 = 65536 ints
#define WS_RWH     82512      // 64*512 bf16 (padded) = 16384 ints
#define WS_RWL     98896      // 16384 ints
#define WS_XH      115280     // 8192*512 bf16 = 2097152 ints
#define WS_XL      2212432    // 8192*512 bf16

__device__ inline float bf2f(short s) {
    return __uint_as_float(((unsigned)(unsigned short)s) << 16);
}

__device__ inline s16x4 pk4(float a, float b, float c, float d) {
    __hip_bfloat162 p0 = __float22bfloat162_rn(make_float2(a, b));
    __hip_bfloat162 p1 = __float22bfloat162_rn(make_float2(c, d));
    union { __hip_bfloat162 h; short2 s; } u0, u1;
    u0.h = p0; u1.h = p1;
    s16x4 r; r[0] = u0.s.x; r[1] = u0.s.y; r[2] = u1.s.x; r[3] = u1.s.y;
    return r;
}

// =====================================================================
// Cooperative mega kernel: cvt -> head -> reorder -> adapted in one launch.
// __launch_bounds__(256,2): cap VGPR<=256 so 2 blocks/CU -> GRID=512 co-resident.
// =====================================================================
__global__ __launch_bounds__(256, 2) void mega(
        const float* __restrict__ x,
        const float* __restrict__ rw, const float* __restrict__ rb,
        const float* __restrict__ ew, const float* __restrict__ eb,
        const float* __restrict__ pw, const float* __restrict__ pbias,
        float* __restrict__ out_idx, float* __restrict__ probs,
        float* __restrict__ out_adapted, float* __restrict__ out_params,
        int* __restrict__ idx_i, int* __restrict__ counts,
        int* __restrict__ cursor, int* __restrict__ order,
        short* __restrict__ pwh, short* __restrict__ rwh, short* __restrict__ rwl,
        short* __restrict__ xh, short* __restrict__ xl) {
    cg::grid_group gg = cg::this_grid();
    __shared__ short smem[4 * TILE_SH];   // 36864 B
    __shared__ int misc[256];
    int bid = blockIdx.x;
    int tid = threadIdx.x;
    int wv = tid >> 6;
    int lane = tid & 63;
    int fm = lane & 15;
    int q = lane >> 4;

    // ================= phase 1: convert x / pw / rw, zero counts+cursor =================
    for (int u = bid; u < CVT_UNITS; u += GRID) {
        if (u < CVT_XB) {
            size_t i = ((size_t)u * 256 + tid) * 4;
            float4 v = *(const float4*)&x[i];
            s16x4 h = pk4(v.x, v.y, v.z, v.w);
            s16x4 l = pk4(v.x - bf2f(h[0]), v.y - bf2f(h[1]),
                          v.z - bf2f(h[2]), v.w - bf2f(h[3]));
            *(s16x4*)&xh[i] = h;
            *(s16x4*)&xl[i] = l;
        } else if (u < CVT_XB + CVT_PWB) {
            size_t i = ((size_t)(u - CVT_XB) * 256 + tid) * 4;
            float4 v = *(const float4*)&pw[i];
            *(s16x4*)&pwh[i] = pk4(v.x, v.y, v.z, v.w);
        } else if (u < CVT_XB + CVT_PWB + CVT_RWB) {
            int i = ((u - CVT_XB - CVT_PWB) * 256 + tid) * 4;  // padded 64x512
            int row = i >> 9;
            float4 v = {0.f, 0.f, 0.f, 0.f};
            if (row < N_TOOLS) v = *(const float4*)&rw[i];
            s16x4 h = pk4(v.x, v.y, v.z, v.w);
            s16x4 l = pk4(v.x - bf2f(h[0]), v.y - bf2f(h[1]),
                          v.z - bf2f(h[2]), v.w - bf2f(h[3]));
            *(s16x4*)&rwh[i] = h;
            *(s16x4*)&rwl[i] = l;
        } else {
            if (tid < 64) { counts[tid] = 0; cursor[tid] = 0; }
        }
    }
    __threadfence();
    gg.sync();

    // ================= phase 2: head (params tiles 0-3, logits tile 4) =================
    {
        short* As = smem;
        short* Bs = smem + TILE_SH;
        short* Al = smem + 2 * TILE_SH;
        short* Bl = smem + 3 * TILE_SH;
        for (int u = bid; u < NHEAD; u += GRID) {
            int tl = u % 5;
            int yy = u / 5;
            int r0 = yy * 64;
            bool isl = (tl == 4);
            int c0 = isl ? 0 : tl * 64;

            int ar0 = tid >> 3, ag = tid & 7;
            int ar1 = ar0 + 32;
            const short* aptr0 = xh + (size_t)(r0 + ar0) * DIM + ag * 8;
            const short* aptr1 = xh + (size_t)(r0 + ar1) * DIM + ag * 8;
            const short* alptr0 = xl + (size_t)(r0 + ar0) * DIM + ag * 8;
            const short* alptr1 = xl + (size_t)(r0 + ar1) * DIM + ag * 8;

            const short* bsrc = isl ? rwh : (pwh + (size_t)c0 * DIM);
            int bc[2], bg[2];
            const short* bph[2];
            const short* bpl[2];
#pragma unroll
            for (int i = 0; i < 2; ++i) {
                int u2 = i * 256 + tid;
                bc[i] = u2 >> 3; bg[i] = u2 & 7;
                bph[i] = bsrc + (size_t)bc[i] * DIM + bg[i] * 8;
                bpl[i] = rwl + (size_t)bc[i] * DIM + bg[i] * 8;
            }

            f32x4 acc[4] = {{0.f, 0.f, 0.f, 0.f}, {0.f, 0.f, 0.f, 0.f},
                            {0.f, 0.f, 0.f, 0.f}, {0.f, 0.f, 0.f, 0.f}};

            s16x8 apre0, apre1, alpre0, alpre1;
            s16x8 bpre[2], blpre[2];
            apre0 = *(const s16x8*)aptr0;
            apre1 = *(const s16x8*)aptr1;
            if (isl) { alpre0 = *(const s16x8*)alptr0; alpre1 = *(const s16x8*)alptr1; }
#pragma unroll
            for (int i = 0; i < 2; ++i) {
                bpre[i] = *(const s16x8*)bph[i];
                if (isl) blpre[i] = *(const s16x8*)bpl[i];
            }

            for (int k0 = 0; k0 < DIM; k0 += 64) {
                *(s16x8*)&As[ar0 * LDSS + ag * 8] = apre0;
                *(s16x8*)&As[ar1 * LDSS + ag * 8] = apre1;
#pragma unroll
                for (int i = 0; i < 2; ++i)
                    *(s16x8*)&Bs[bc[i] * LDSS + bg[i] * 8] = bpre[i];
                if (isl) {
                    *(s16x8*)&Al[ar0 * LDSS + ag * 8] = alpre0;
                    *(s16x8*)&Al[ar1 * LDSS + ag * 8] = alpre1;
#pragma unroll
                    for (int i = 0; i < 2; ++i)
                        *(s16x8*)&Bl[bc[i] * LDSS + bg[i] * 8] = blpre[i];
                }
                __syncthreads();

                int kn = k0 + 64;
                if (kn < DIM) {
                    apre0 = *(const s16x8*)(aptr0 + kn);
                    apre1 = *(const s16x8*)(aptr1 + kn);
                    if (isl) {
                        alpre0 = *(const s16x8*)(alptr0 + kn);
                        alpre1 = *(const s16x8*)(alptr1 + kn);
                    }
#pragma unroll
                    for (int i = 0; i < 2; ++i) {
                        bpre[i] = *(const s16x8*)(bph[i] + kn);
                        if (isl) blpre[i] = *(const s16x8*)(bpl[i] + kn);
                    }
                }

#pragma unroll
                for (int kk = 0; kk < 64; kk += 32) {
                    int ao = (wv * 16 + fm) * LDSS + kk + q * 8;
                    s16x8 a = *(const s16x8*)&As[ao];
                    if (!isl) {
#pragma unroll
                        for (int n = 0; n < 4; ++n) {
                            s16x8 b = *(const s16x8*)&Bs[(n * 16 + fm) * LDSS + kk + q * 8];
                            acc[n] = __builtin_amdgcn_mfma_f32_16x16x32_bf16(a, b, acc[n], 0, 0, 0);
                        }
                    } else {
                        s16x8 al = *(const s16x8*)&Al[ao];
#pragma unroll
                        for (int n = 0; n < 4; ++n) {
                            int bo = (n * 16 + fm) * LDSS + kk + q * 8;
                            s16x8 b  = *(const s16x8*)&Bs[bo];
                            s16x8 bl = *(const s16x8*)&Bl[bo];
                            acc[n] = __builtin_amdgcn_mfma_f32_16x16x32_bf16(a,  b,  acc[n], 0, 0, 0);
                            acc[n] = __builtin_amdgcn_mfma_f32_16x16x32_bf16(a,  bl, acc[n], 0, 0, 0);
                            acc[n] = __builtin_amdgcn_mfma_f32_16x16x32_bf16(al, b,  acc[n], 0, 0, 0);
                        }
                    }
                }
                __syncthreads();
            }

            if (!isl) {
                float bias[4];
#pragma unroll
                for (int n = 0; n < 4; ++n) bias[n] = pbias[c0 + n * 16 + fm];
#pragma unroll
                for (int r = 0; r < 4; ++r) {
                    int row = r0 + wv * 16 + q * 4 + r;
                    float* op = out_params + (size_t)row * PARAM_DIM + c0;
#pragma unroll
                    for (int n = 0; n < 4; ++n) op[n * 16 + fm] = acc[n][r] + bias[n];
                }
            } else {
                float rbv[4];
#pragma unroll
                for (int n = 0; n < 4; ++n) {
                    int c = n * 16 + fm;
                    rbv[n] = (c < N_TOOLS) ? rb[c] : 0.f;
                }
#pragma unroll
                for (int rr = 0; rr < 4; ++rr) {
                    int row_l = wv * 16 + q * 4 + rr;
                    int row = r0 + row_l;
                    float v[4];
                    float vmax = -INFINITY; int vcol = N_TOOLS;
#pragma unroll
                    for (int n = 0; n < 4; ++n) {
                        int c = n * 16 + fm;
                        v[n] = acc[n][rr] + rbv[n];
                        if (c < N_TOOLS && v[n] > vmax) { vmax = v[n]; vcol = c; }
                    }
#pragma unroll
                    for (int s = 1; s < 16; s <<= 1) {
                        float om = __shfl_xor(vmax, s, 64);
                        int   oc = __shfl_xor(vcol, s, 64);
                        if (om > vmax || (om == vmax && oc < vcol)) { vmax = om; vcol = oc; }
                    }
                    float e[4]; float esum = 0.f;
#pragma unroll
                    for (int n = 0; n < 4; ++n) {
                        int c = n * 16 + fm;
                        e[n] = (c < N_TOOLS) ? expf(v[n] - vmax) : 0.f;
                        esum += e[n];
                    }
#pragma unroll
                    for (int s = 1; s < 16; s <<= 1) esum += __shfl_xor(esum, s, 64);
                    float inv = 1.f / esum;
#pragma unroll
                    for (int n = 0; n < 4; ++n) {
                        int c = n * 16 + fm;
                        if (c < N_TOOLS) probs[(size_t)row * N_TOOLS + c] = e[n] * inv;
                    }
                    if (fm == 0) {
                        out_idx[row] = (float)vcol;
                        idx_i[row] = vcol;
                        misc[row_l] = vcol;
                    }
                }
                __syncthreads();   // isl is block-uniform
                if (wv == 0) {
                    int myc = misc[lane];
                    int cnt = 0;
                    for (int e2 = 0; e2 < N_TOOLS; ++e2) {
                        unsigned long long m = __ballot(myc == e2);
                        if (lane == e2) cnt = __popcll(m);
                    }
                    if (lane < N_TOOLS && cnt > 0) atomicAdd(&counts[lane], cnt);
                }
            }
            __syncthreads();   // unit separation
        }
    }
    __threadfence();
    gg.sync();

    // ================= phase 3: reorder (32 units; in-block offsets scan) =================
    for (int u = bid; u < N_TOKENS / 256; u += GRID) {
        if (tid < N_TOOLS) misc[tid] = 0;          // lcnt
        if (wv == 1) {                              // wave 1: exclusive scan of counts
            int c = (lane < N_TOOLS) ? counts[lane] : 0;
            int pre = c;
#pragma unroll
            for (int s = 1; s < 64; s <<= 1) {
                int v = __shfl_up(pre, s, 64);
                if (lane >= s) pre += v;
            }
            misc[64 + lane] = pre - c;             // offsets
        }
        __syncthreads();
        int t = u * 256 + tid;
        int e = idx_i[t];
        int r = atomicAdd(&misc[e], 1);
        __syncthreads();
        if (tid < N_TOOLS) {
            int c2 = misc[tid];
            misc[128 + tid] = (c2 > 0) ? atomicAdd(&cursor[tid], c2) : 0;
        }
        __syncthreads();
        order[misc[64 + e] + misc[128 + e] + r] = t;
        __syncthreads();
    }
    __threadfence();
    gg.sync();

    // ================= phase 4: adapted grouped GEMM (TM=128, in-block batch derivation) =================
    {
        short* As = smem;                  // 128 x LDSS
        short* Bs = smem + 2 * TILE_SH;    // 64 x LDSS
        for (int u = bid; u < MAXB * 8; u += GRID) {
            int b = u >> 3;
            int ct = u & 7;
            __syncthreads();
            if (tid < 64) misc[128 + tid] = (tid < N_TOOLS) ? counts[tid] : 0;
            __syncthreads();
            int e = -1, m0 = 0, off = 0;
            int accb = 0, acco = 0;
            for (int i = 0; i < N_TOOLS; ++i) {
                int c = misc[128 + i];
                int nb = (c + TM - 1) >> 7;
                if (e < 0 && b < accb + nb) { e = i; m0 = (b - accb) * TM; off = acco; }
                accb += nb; acco += c;
            }
            if (e < 0) continue;   // b >= nb_total (block-uniform)
            int c0 = ct * 64;
            int start = off + m0;
            int len = misc[128 + e] - m0;
            if (len > TM) len = TM;

            if (tid < TM) misc[tid] = (tid < len) ? order[start + tid] : -1;
            __syncthreads();

            const float* We = ew + (size_t)e * DIM * DIM;

            int ag = tid & 7;
            int ar[4]; const short* aptr[4];
#pragma unroll
            for (int i = 0; i < 4; ++i) {
                ar[i] = i * 32 + (tid >> 3);
                int tk = misc[ar[i]];
                aptr[i] = (tk >= 0) ? xh + (size_t)tk * DIM + ag * 8 : nullptr;
            }
            int bc[4], bg[4];
            const float* bptr[4];
#pragma unroll
            for (int i = 0; i < 4; ++i) {
                int u2 = i * 256 + tid;
                bc[i] = u2 >> 4; bg[i] = u2 & 15;
                bptr[i] = We + (size_t)(c0 + bc[i]) * DIM + bg[i] * 4;
            }

            f32x4 acc[8] = {{0.f,0.f,0.f,0.f},{0.f,0.f,0.f,0.f},{0.f,0.f,0.f,0.f},{0.f,0.f,0.f,0.f},
                            {0.f,0.f,0.f,0.f},{0.f,0.f,0.f,0.f},{0.f,0.f,0.f,0.f},{0.f,0.f,0.f,0.f}};

            const s16x8 z8 = {0, 0, 0, 0, 0, 0, 0, 0};
            s16x8 apre[4];
            float4 bpre[4];
#pragma unroll
            for (int i = 0; i < 4; ++i) apre[i] = aptr[i] ? *(const s16x8*)aptr[i] : z8;
#pragma unroll
            for (int i = 0; i < 4; ++i) bpre[i] = *(const float4*)bptr[i];

            for (int k0 = 0; k0 < DIM; k0 += 64) {
#pragma unroll
                for (int i = 0; i < 4; ++i)
                    *(s16x8*)&As[ar[i] * LDSS + ag * 8] = apre[i];
#pragma unroll
                for (int i = 0; i < 4; ++i) {
                    float4 v = bpre[i];
                    *(s16x4*)&Bs[bc[i] * LDSS + bg[i] * 4] = pk4(v.x, v.y, v.z, v.w);
                }
                __syncthreads();

                int kn = k0 + 64;
                if (kn < DIM) {
#pragma unroll
                    for (int i = 0; i < 4; ++i) apre[i] = aptr[i] ? *(const s16x8*)(aptr[i] + kn) : z8;
#pragma unroll
                    for (int i = 0; i < 4; ++i) bpre[i] = *(const float4*)(bptr[i] + kn);
                }

#pragma unroll
                for (int kk = 0; kk < 64; kk += 32) {
                    s16x8 a0 = *(const s16x8*)&As[(wv * 32 + fm) * LDSS + kk + q * 8];
                    s16x8 a1 = *(const s16x8*)&As[(wv * 32 + 16 + fm) * LDSS + kk + q * 8];
#pragma unroll
                    for (int n = 0; n < 4; ++n) {
                        s16x8 bf = *(const s16x8*)&Bs[(n * 16 + fm) * LDSS + kk + q * 8];
                        acc[n]     = __builtin_amdgcn_mfma_f32_16x16x32_bf16(a0, bf, acc[n],     0, 0, 0);
                        acc[4 + n] = __builtin_amdgcn_mfma_f32_16x16x32_bf16(a1, bf, acc[4 + n], 0, 0, 0);
                    }
                }
                __syncthreads();
            }

            float bias[4];
#pragma unroll
            for (int n = 0; n < 4; ++n) bias[n] = eb[(size_t)e * DIM + c0 + n * 16 + fm];

#pragma unroll
            for (int m = 0; m < 2; ++m) {
#pragma unroll
                for (int r = 0; r < 4; ++r) {
                    int row = wv * 32 + m * 16 + q * 4 + r;
                    int tok = misc[row];
                    if (tok < 0) continue;
                    float* op = out_adapted + (size_t)tok * DIM + c0;
#pragma unroll
                    for (int n = 0; n < 4; ++n) op[n * 16 + fm] = acc[m * 4 + n][r] + bias[n];
                }
            }
        }
    }
}

// =====================================================================
// Fallback chain (round-1 proven kernels, 152.3 us) — used only if the
// cooperative launch is rejected by the runtime.
// =====================================================================
__global__ __launch_bounds__(256) void cvt_kernel(const float* __restrict__ x,
                                                  const float* __restrict__ pw,
                                                  const float* __restrict__ rw,
                                                  short* __restrict__ xh,
                                                  short* __restrict__ xl,
                                                  short* __restrict__ pwh,
                                                  short* __restrict__ rwh,
                                                  short* __restrict__ rwl,
                                                  int* __restrict__ counts) {
    int bid = blockIdx.x;
    int tid = threadIdx.x;
    if (bid < CVT_XB) {
        size_t i = ((size_t)bid * 256 + tid) * 4;
        float4 v = *(const float4*)&x[i];
        s16x4 h = pk4(v.x, v.y, v.z, v.w);
        s16x4 l = pk4(v.x - bf2f(h[0]), v.y - bf2f(h[1]),
                      v.z - bf2f(h[2]), v.w - bf2f(h[3]));
        *(s16x4*)&xh[i] = h;
        *(s16x4*)&xl[i] = l;
    } else if (bid < CVT_XB + CVT_PWB) {
        size_t i = ((size_t)(bid - CVT_XB) * 256 + tid) * 4;
        float4 v = *(const float4*)&pw[i];
        *(s16x4*)&pwh[i] = pk4(v.x, v.y, v.z, v.w);
    } else if (bid < CVT_XB + CVT_PWB + CVT_RWB) {
        int i = ((bid - CVT_XB - CVT_PWB) * 256 + tid) * 4;
        int row = i >> 9;
        float4 v = {0.f, 0.f, 0.f, 0.f};
        if (row < N_TOOLS) v = *(const float4*)&rw[i];
        s16x4 h = pk4(v.x, v.y, v.z, v.w);
        s16x4 l = pk4(v.x - bf2f(h[0]), v.y - bf2f(h[1]),
                      v.z - bf2f(h[2]), v.w - bf2f(h[3]));
        *(s16x4*)&rwh[i] = h;
        *(s16x4*)&rwl[i] = l;
    } else {
        if (tid < 64) counts[tid] = 0;
    }
}

__global__ __launch_bounds__(256) void head_mfma(const short* __restrict__ xh,
                                                 const short* __restrict__ xl,
                                                 const short* __restrict__ pwh,
                                                 const float* __restrict__ pb,
                                                 const short* __restrict__ rwh,
                                                 const short* __restrict__ rwl,
                                                 const float* __restrict__ rb,
                                                 float* __restrict__ out_params,
                                                 float* __restrict__ probs,
                                                 float* __restrict__ out_idx,
                                                 int* __restrict__ idx_i,
                                                 int* __restrict__ counts) {
    int r0 = blockIdx.y * 64;
    bool isl = (blockIdx.x == 4);
    int c0 = isl ? 0 : blockIdx.x * 64;

    __shared__ short As[64 * LDSS];
    __shared__ short Bs[64 * LDSS];
    __shared__ short Al[64 * LDSS];
    __shared__ short Bl[64 * LDSS];
    __shared__ int rowcol[64];

    int tid = threadIdx.x;
    int wv = tid >> 6;
    int lane = tid & 63;
    int fm = lane & 15;
    int q = lane >> 4;

    int ar0 = tid >> 3, ag = tid & 7;
    int ar1 = ar0 + 32;
    const short* aptr0 = xh + (size_t)(r0 + ar0) * DIM + ag * 8;
    const short* aptr1 = xh + (size_t)(r0 + ar1) * DIM + ag * 8;
    const short* alptr0 = xl + (size_t)(r0 + ar0) * DIM + ag * 8;
    const short* alptr1 = xl + (size_t)(r0 + ar1) * DIM + ag * 8;

    const short* bsrc = isl ? rwh : (pwh + (size_t)c0 * DIM);
    int bc[2], bg[2];
    const short* bph[2];
    const short* bpl[2];
#pragma unroll
    for (int i = 0; i < 2; ++i) {
        int u = i * 256 + tid;
        bc[i] = u >> 3; bg[i] = u & 7;
        bph[i] = bsrc + (size_t)bc[i] * DIM + bg[i] * 8;
        bpl[i] = rwl + (size_t)bc[i] * DIM + bg[i] * 8;
    }

    f32x4 acc[4] = {{0.f, 0.f, 0.f, 0.f}, {0.f, 0.f, 0.f, 0.f},
                    {0.f, 0.f, 0.f, 0.f}, {0.f, 0.f, 0.f, 0.f}};

    s16x8 apre0, apre1, alpre0, alpre1;
    s16x8 bpre[2], blpre[2];
    apre0 = *(const s16x8*)aptr0;
    apre1 = *(const s16x8*)aptr1;
    if (isl) { alpre0 = *(const s16x8*)alptr0; alpre1 = *(const s16x8*)alptr1; }
#pragma unroll
    for (int i = 0; i < 2; ++i) {
        bpre[i] = *(const s16x8*)bph[i];
        if (isl) blpre[i] = *(const s16x8*)bpl[i];
    }

    for (int k0 = 0; k0 < DIM; k0 += 64) {
        *(s16x8*)&As[ar0 * LDSS + ag * 8] = apre0;
        *(s16x8*)&As[ar1 * LDSS + ag * 8] = apre1;
#pragma unroll
        for (int i = 0; i < 2; ++i)
            *(s16x8*)&Bs[bc[i] * LDSS + bg[i] * 8] = bpre[i];
        if (isl) {
            *(s16x8*)&Al[ar0 * LDSS + ag * 8] = alpre0;
            *(s16x8*)&Al[ar1 * LDSS + ag * 8] = alpre1;
#pragma unroll
            for (int i = 0; i < 2; ++i)
                *(s16x8*)&Bl[bc[i] * LDSS + bg[i] * 8] = blpre[i];
        }
        __syncthreads();

        int kn = k0 + 64;
        if (kn < DIM) {
            apre0 = *(const s16x8*)(aptr0 + kn);
            apre1 = *(const s16x8*)(aptr1 + kn);
            if (isl) {
                alpre0 = *(const s16x8*)(alptr0 + kn);
                alpre1 = *(const s16x8*)(alptr1 + kn);
            }
#pragma unroll
            for (int i = 0; i < 2; ++i) {
                bpre[i] = *(const s16x8*)(bph[i] + kn);
                if (isl) blpre[i] = *(const s16x8*)(bpl[i] + kn);
            }
        }

#pragma unroll
        for (int kk = 0; kk < 64; kk += 32) {
            int ao = (wv * 16 + fm) * LDSS + kk + q * 8;
            s16x8 a = *(const s16x8*)&As[ao];
            if (!isl) {
#pragma unroll
                for (int n = 0; n < 4; ++n) {
                    s16x8 b = *(const s16x8*)&Bs[(n * 16 + fm) * LDSS + kk + q * 8];
                    acc[n] = __builtin_amdgcn_mfma_f32_16x16x32_bf16(a, b, acc[n], 0, 0, 0);
                }
            } else {
                s16x8 al = *(const s16x8*)&Al[ao];
#pragma unroll
                for (int n = 0; n < 4; ++n) {
                    int bo = (n * 16 + fm) * LDSS + kk + q * 8;
                    s16x8 b  = *(const s16x8*)&Bs[bo];
                    s16x8 bl = *(const s16x8*)&Bl[bo];
                    acc[n] = __builtin_amdgcn_mfma_f32_16x16x32_bf16(a,  b,  acc[n], 0, 0, 0);
                    acc[n] = __builtin_amdgcn_mfma_f32_16x16x32_bf16(a,  bl, acc[n], 0, 0, 0);
                    acc[n] = __builtin_amdgcn_mfma_f32_16x16x32_bf16(al, b,  acc[n], 0, 0, 0);
                }
            }
        }
        __syncthreads();
    }

    if (!isl) {
        float bias[4];
#pragma unroll
        for (int n = 0; n < 4; ++n) bias[n] = pb[c0 + n * 16 + fm];
#pragma unroll
        for (int r = 0; r < 4; ++r) {
            int row = r0 + wv * 16 + q * 4 + r;
            float* op = out_params + (size_t)row * PARAM_DIM + c0;
#pragma unroll
            for (int n = 0; n < 4; ++n) op[n * 16 + fm] = acc[n][r] + bias[n];
        }
    } else {
        float rbv[4];
#pragma unroll
        for (int n = 0; n < 4; ++n) {
            int c = n * 16 + fm;
            rbv[n] = (c < N_TOOLS) ? rb[c] : 0.f;
        }
#pragma unroll
        for (int rr = 0; rr < 4; ++rr) {
            int row_l = wv * 16 + q * 4 + rr;
            int row = r0 + row_l;
            float v[4];
            float vmax = -INFINITY; int vcol = N_TOOLS;
#pragma unroll
            for (int n = 0; n < 4; ++n) {
                int c = n * 16 + fm;
                v[n] = acc[n][rr] + rbv[n];
                if (c < N_TOOLS && v[n] > vmax) { vmax = v[n]; vcol = c; }
            }
#pragma unroll
            for (int s = 1; s < 16; s <<= 1) {
                float om = __shfl_xor(vmax, s, 64);
                int   oc = __shfl_xor(vcol, s, 64);
                if (om > vmax || (om == vmax && oc < vcol)) { vmax = om; vcol = oc; }
            }
            float e[4]; float esum = 0.f;
#pragma unroll
            for (int n = 0; n < 4; ++n) {
                int c = n * 16 + fm;
                e[n] = (c < N_TOOLS) ? expf(v[n] - vmax) : 0.f;
                esum += e[n];
            }
#pragma unroll
            for (int s = 1; s < 16; s <<= 1) esum += __shfl_xor(esum, s, 64);
            float inv = 1.f / esum;
#pragma unroll
            for (int n = 0; n < 4; ++n) {
                int c = n * 16 + fm;
                if (c < N_TOOLS) probs[(size_t)row * N_TOOLS + c] = e[n] * inv;
            }
            if (fm == 0) {
                out_idx[row] = (float)vcol;
                idx_i[row] = vcol;
                rowcol[row_l] = vcol;
            }
        }
        __syncthreads();
        if (wv == 0) {
            int myc = rowcol[lane];
            int cnt = 0;
            for (int e2 = 0; e2 < N_TOOLS; ++e2) {
                unsigned long long m = __ballot(myc == e2);
                if (lane == e2) cnt = __popcll(m);
            }
            if (lane < N_TOOLS && cnt > 0) atomicAdd(&counts[lane], cnt);
        }
    }
}

__global__ void plumb_kernel(const int* __restrict__ counts,
                             int* __restrict__ offsets,
                             int* __restrict__ cursor,
                             int* __restrict__ batch_e,
                             int* __restrict__ batch_m0,
                             int* __restrict__ nb_out) {
    int lane = threadIdx.x;   // 64
    int c = (lane < N_TOOLS) ? counts[lane] : 0;
    int pre = c;
#pragma unroll
    for (int s = 1; s < 64; s <<= 1) {
        int v = __shfl_up(pre, s, 64);
        if (lane >= s) pre += v;
    }
    if (lane < N_TOOLS) { offsets[lane] = pre - c; cursor[lane] = pre - c; }

    int nb_i = (lane < N_TOOLS) ? (c + TM - 1) / TM : 0;
    int pre2 = nb_i;
#pragma unroll
    for (int s = 1; s < 64; s <<= 1) {
        int v = __shfl_up(pre2, s, 64);
        if (lane >= s) pre2 += v;
    }
    int bstart = pre2 - nb_i;
    for (int b = 0; b < nb_i; ++b) {
        batch_e[bstart + b] = lane;
        batch_m0[bstart + b] = b * TM;
    }
    if (lane == 63) nb_out[0] = pre2;
}

__global__ __launch_bounds__(256) void reorder_kernel(const int* __restrict__ idx_i,
                                                      int* __restrict__ cursor,
                                                      int* __restrict__ order) {
    __shared__ int lcnt[N_TOOLS];
    __shared__ int lbase[N_TOOLS];
    int tid = threadIdx.x;
    if (tid < N_TOOLS) lcnt[tid] = 0;
    __syncthreads();
    int t = blockIdx.x * 256 + tid;
    int e = idx_i[t];
    int r = atomicAdd(&lcnt[e], 1);
    __syncthreads();
    if (tid < N_TOOLS && lcnt[tid] > 0) lbase[tid] = atomicAdd(&cursor[tid], lcnt[tid]);
    __syncthreads();
    order[lbase[e] + r] = t;
}

__global__ __launch_bounds__(256) void adapted_mfma(const short* __restrict__ xh,
                                                    const float* __restrict__ ew,
                                                    const float* __restrict__ eb,
                                                    const int* __restrict__ order,
                                                    const int* __restrict__ batch_e,
                                                    const int* __restrict__ batch_m0,
                                                    const int* __restrict__ nb_ptr,
                                                    const int* __restrict__ offsets,
                                                    const int* __restrict__ counts,
                                                    float* __restrict__ out) {
    int b = blockIdx.y;
    if (b >= nb_ptr[0]) return;
    int e = batch_e[b];
    int m0 = batch_m0[b];
    int c0 = blockIdx.x * 64;
    int start = offsets[e] + m0;
    int len = counts[e] - m0;
    if (len > TM) len = TM;

    __shared__ short As[TM * LDSS];
    __shared__ short Bs[64 * LDSS];
    __shared__ int toks[TM];

    int tid = threadIdx.x;
    if (tid < TM) toks[tid] = (tid < len) ? order[start + tid] : -1;
    __syncthreads();

    int wv = tid >> 6;
    int lane = tid & 63;
    int fm = lane & 15;
    int q = lane >> 4;

    const float* We = ew + (size_t)e * DIM * DIM;

    int ag = tid & 7;
    int ar[4]; const short* aptr[4];
#pragma unroll
    for (int i = 0; i < 4; ++i) {
        ar[i] = i * 32 + (tid >> 3);
        int tk = toks[ar[i]];
        aptr[i] = (tk >= 0) ? xh + (size_t)tk * DIM + ag * 8 : nullptr;
    }
    int bc[4], bg[4];
    const float* bptr[4];
#pragma unroll
    for (int i = 0; i < 4; ++i) {
        int u = i * 256 + tid;
        bc[i] = u >> 4; bg[i] = u & 15;
        bptr[i] = We + (size_t)(c0 + bc[i]) * DIM + bg[i] * 4;
    }

    f32x4 acc[8] = {{0.f,0.f,0.f,0.f},{0.f,0.f,0.f,0.f},{0.f,0.f,0.f,0.f},{0.f,0.f,0.f,0.f},
                    {0.f,0.f,0.f,0.f},{0.f,0.f,0.f,0.f},{0.f,0.f,0.f,0.f},{0.f,0.f,0.f,0.f}};

    const s16x8 z8 = {0, 0, 0, 0, 0, 0, 0, 0};
    s16x8 apre[4];
    float4 bpre[4];
#pragma unroll
    for (int i = 0; i < 4; ++i) apre[i] = aptr[i] ? *(const s16x8*)aptr[i] : z8;
#pragma unroll
    for (int i = 0; i < 4; ++i) bpre[i] = *(const float4*)bptr[i];

    for (int k0 = 0; k0 < DIM; k0 += 64) {
#pragma unroll
        for (int i = 0; i < 4; ++i)
            *(s16x8*)&As[ar[i] * LDSS + ag * 8] = apre[i];
#pragma unroll
        for (int i = 0; i < 4; ++i) {
            float4 v = bpre[i];
            *(s16x4*)&Bs[bc[i] * LDSS + bg[i] * 4] = pk4(v.x, v.y, v.z, v.w);
        }
        __syncthreads();

        int kn = k0 + 64;
        if (kn < DIM) {
#pragma unroll
            for (int i = 0; i < 4; ++i) apre[i] = aptr[i] ? *(const s16x8*)(aptr[i] + kn) : z8;
#pragma unroll
            for (int i = 0; i < 4; ++i) bpre[i] = *(const float4*)(bptr[i] + kn);
        }

#pragma unroll
        for (int kk = 0; kk < 64; kk += 32) {
            s16x8 a0 = *(const s16x8*)&As[(wv * 32 + fm) * LDSS + kk + q * 8];
            s16x8 a1 = *(const s16x8*)&As[(wv * 32 + 16 + fm) * LDSS + kk + q * 8];
#pragma unroll
            for (int n = 0; n < 4; ++n) {
                s16x8 bf = *(const s16x8*)&Bs[(n * 16 + fm) * LDSS + kk + q * 8];
                acc[n]     = __builtin_amdgcn_mfma_f32_16x16x32_bf16(a0, bf, acc[n],     0, 0, 0);
                acc[4 + n] = __builtin_amdgcn_mfma_f32_16x16x32_bf16(a1, bf, acc[4 + n], 0, 0, 0);
            }
        }
        __syncthreads();
    }

    float bias[4];
#pragma unroll
    for (int n = 0; n < 4; ++n) bias[n] = eb[(size_t)e * DIM + c0 + n * 16 + fm];

#pragma unroll
    for (int m = 0; m < 2; ++m) {
#pragma unroll
        for (int r = 0; r < 4; ++r) {
            int row = wv * 32 + m * 16 + q * 4 + r;
            int tok = toks[row];
            if (tok < 0) continue;
            float* op = out + (size_t)tok * DIM + c0;
#pragma unroll
            for (int n = 0; n < 4; ++n) op[n * 16 + fm] = acc[m * 4 + n][r] + bias[n];
        }
    }
}

extern "C" void kernel_launch(void* const* d_in, const int* in_sizes, int n_in,
                              void* d_out, int out_size, void* d_ws, size_t ws_size,
                              hipStream_t stream) {
    const float* x        = (const float*)d_in[0];
    const float* router_w = (const float*)d_in[1];
    const float* router_b = (const float*)d_in[2];
    const float* expert_w = (const float*)d_in[3];
    const float* expert_b = (const float*)d_in[4];
    const float* param_w  = (const float*)d_in[5];
    const float* param_b  = (const float*)d_in[6];

    float* out = (float*)d_out;
    float* out_idx     = out;                                  // 8192
    float* out_probs   = out + N_TOKENS;                       // 409600
    float* out_adapted = out + N_TOKENS + N_TOKENS * N_TOOLS;  // 4194304
    float* out_params  = out_adapted + (size_t)N_TOKENS * DIM; // 2097152

    int* ws = (int*)d_ws;
    int* ws_idx     = ws + WS_IDX;
    int* ws_counts  = ws + WS_COUNTS;
    int* ws_cursor  = ws + WS_CURSOR;
    int* ws_offsets = ws + WS_OFFSETS;
    int* ws_be      = ws + WS_BE;
    int* ws_bm0     = ws + WS_BM0;
    int* ws_nb      = ws + WS_NB;
    int* ws_order   = ws + WS_ORDER;
    short* ws_pwh   = (short*)(ws + WS_PWH);
    short* ws_rwh   = (short*)(ws + WS_RWH);
    short* ws_rwl   = (short*)(ws + WS_RWL);
    short* ws_xh    = (short*)(ws + WS_XH);
    short* ws_xl    = (short*)(ws + WS_XL);

    void* args[] = {
        (void*)&x, (void*)&router_w, (void*)&router_b,
        (void*)&expert_w, (void*)&expert_b,
        (void*)&param_w, (void*)&param_b,
        (void*)&out_idx, (void*)&out_probs, (void*)&out_adapted, (void*)&out_params,
        (void*)&ws_idx, (void*)&ws_counts, (void*)&ws_cursor, (void*)&ws_order,
        (void*)&ws_pwh, (void*)&ws_rwh, (void*)&ws_rwl, (void*)&ws_xh, (void*)&ws_xl
    };
    hipError_t err = hipLaunchCooperativeKernel((void*)mega, dim3(GRID), dim3(256),
                                                args, 0, stream);
    if (err != hipSuccess) {
        // fallback: proven 5-kernel chain
        cvt_kernel<<<CVT_UNITS, 256, 0, stream>>>(x, param_w, router_w,
                                                  ws_xh, ws_xl, ws_pwh, ws_rwh, ws_rwl,
                                                  ws_counts);
        head_mfma<<<dim3(5, N_ROWBLK), 256, 0, stream>>>(ws_xh, ws_xl, ws_pwh, param_b,
                                                         ws_rwh, ws_rwl, router_b,
                                                         out_params, out_probs,
                                                         out_idx, ws_idx, ws_counts);
        plumb_kernel<<<1, 64, 0, stream>>>(ws_counts, ws_offsets, ws_cursor,
                                           ws_be, ws_bm0, ws_nb);
        reorder_kernel<<<N_TOKENS / 256, 256, 0, stream>>>(ws_idx, ws_cursor, ws_order);
        adapted_mfma<<<dim3(8, MAXB), 256, 0, stream>>>(ws_xh, expert_w, expert_b,
                                                        ws_order, ws_be, ws_bm0, ws_nb,
                                                        ws_offsets, ws_counts, out_adapted);
    }
}

// Round 6
// 152.301 us; speedup vs baseline: 3.0193x; 3.0193x over previous
//
#include <hip/hip_runtime.h>
#include <hip/hip_bf16.h>
#include <math.h>

#define N_TOKENS 8192
#define DIM      512
#define N_TOOLS  50
#define PARAM_DIM 256
#define N_ROWBLK (N_TOKENS / 64)   // 128
#define MAXB 192
#define TM 128                     // adapted M-tile
#define LDSS 72   // LDS inner stride in bf16 elems (144 B -> 2-way bank aliasing max, free)

typedef float  f32x4 __attribute__((ext_vector_type(4)));
typedef short  s16x8 __attribute__((ext_vector_type(8)));
typedef short  s16x4 __attribute__((ext_vector_type(4)));

// ---- workspace layout (ints) ----
#define WS_IDX     0          // 8192  token -> expert
#define WS_COUNTS  8192       // 64    per-expert totals (atomic)
#define WS_CURSOR  8256       // 64    placement cursors (start at 0)
#define WS_ORDER   8320       // 8192
#define WS_PWH     16512      // param_w bf16 hi: 256*512 shorts = 65536 ints
#define WS_RWH     82048      // router_w bf16 hi, padded 64x512: 16384 ints
#define WS_RWL     98432      // router_w bf16 lo: 16384 ints
#define WS_XH      114816     // 8192*512 bf16 hi = 2097152 ints
#define WS_XL      2211968    // 8192*512 bf16 lo

__device__ inline float bf2f(short s) {
    return __uint_as_float(((unsigned)(unsigned short)s) << 16);
}

__device__ inline s16x4 pk4(float a, float b, float c, float d) {
    __hip_bfloat162 p0 = __float22bfloat162_rn(make_float2(a, b));
    __hip_bfloat162 p1 = __float22bfloat162_rn(make_float2(c, d));
    union { __hip_bfloat162 h; short2 s; } u0, u1;
    u0.h = p0; u1.h = p1;
    s16x4 r; r[0] = u0.s.x; r[1] = u0.s.y; r[2] = u1.s.x; r[3] = u1.s.y;
    return r;
}

// ---------------- pre-convert: x (hi+lo), param_w (hi), router_w (hi+lo, 64-row pad), zero counts+cursor ----------------
#define CVT_XB  4096
#define CVT_PWB 128
#define CVT_RWB 32
#define CVT_GRID (CVT_XB + CVT_PWB + CVT_RWB + 1)
__global__ __launch_bounds__(256) void cvt_kernel(const float* __restrict__ x,
                                                  const float* __restrict__ pw,
                                                  const float* __restrict__ rw,
                                                  short* __restrict__ xh,
                                                  short* __restrict__ xl,
                                                  short* __restrict__ pwh,
                                                  short* __restrict__ rwh,
                                                  short* __restrict__ rwl,
                                                  int* __restrict__ counts,
                                                  int* __restrict__ cursor) {
    int bid = blockIdx.x;
    int tid = threadIdx.x;
    if (bid < CVT_XB) {
        size_t i = ((size_t)bid * 256 + tid) * 4;
        float4 v = *(const float4*)&x[i];
        s16x4 h = pk4(v.x, v.y, v.z, v.w);
        s16x4 l = pk4(v.x - bf2f(h[0]), v.y - bf2f(h[1]),
                      v.z - bf2f(h[2]), v.w - bf2f(h[3]));
        *(s16x4*)&xh[i] = h;
        *(s16x4*)&xl[i] = l;
    } else if (bid < CVT_XB + CVT_PWB) {
        size_t i = ((size_t)(bid - CVT_XB) * 256 + tid) * 4;
        float4 v = *(const float4*)&pw[i];
        *(s16x4*)&pwh[i] = pk4(v.x, v.y, v.z, v.w);
    } else if (bid < CVT_XB + CVT_PWB + CVT_RWB) {
        int i = ((bid - CVT_XB - CVT_PWB) * 256 + tid) * 4;   // 0..32767 in padded 64x512
        int row = i >> 9;
        float4 v = {0.f, 0.f, 0.f, 0.f};
        if (row < N_TOOLS) v = *(const float4*)&rw[i];
        s16x4 h = pk4(v.x, v.y, v.z, v.w);
        s16x4 l = pk4(v.x - bf2f(h[0]), v.y - bf2f(h[1]),
                      v.z - bf2f(h[2]), v.w - bf2f(h[3]));
        *(s16x4*)&rwh[i] = h;
        *(s16x4*)&rwl[i] = l;
    } else {
        if (tid < 64) { counts[tid] = 0; cursor[tid] = 0; }
    }
}

// ---------------- fused head: params (tiles 0-3) + logits/softmax/argmax (tile 4) ----------------
// grid (5, 128), block 256 (4 waves). Tile 64x64, BK=64, register-prefetch pipeline.
__global__ __launch_bounds__(256) void head_mfma(const short* __restrict__ xh,
                                                 const short* __restrict__ xl,
                                                 const short* __restrict__ pwh,
                                                 const float* __restrict__ pb,
                                                 const short* __restrict__ rwh,
                                                 const short* __restrict__ rwl,
                                                 const float* __restrict__ rb,
                                                 float* __restrict__ out_params,
                                                 float* __restrict__ probs,
                                                 float* __restrict__ out_idx,
                                                 int* __restrict__ idx_i,
                                                 int* __restrict__ counts) {
    int r0 = blockIdx.y * 64;
    bool isl = (blockIdx.x == 4);
    int c0 = isl ? 0 : blockIdx.x * 64;

    __shared__ short As[64 * LDSS];
    __shared__ short Bs[64 * LDSS];
    __shared__ short Al[64 * LDSS];   // lo parts, logits tile only
    __shared__ short Bl[64 * LDSS];
    __shared__ int rowcol[64];

    int tid = threadIdx.x;
    int wv = tid >> 6;
    int lane = tid & 63;
    int fm = lane & 15;
    int q = lane >> 4;

    int ar0 = tid >> 3, ag = tid & 7;
    int ar1 = ar0 + 32;
    const short* aptr0 = xh + (size_t)(r0 + ar0) * DIM + ag * 8;
    const short* aptr1 = xh + (size_t)(r0 + ar1) * DIM + ag * 8;
    const short* alptr0 = xl + (size_t)(r0 + ar0) * DIM + ag * 8;
    const short* alptr1 = xl + (size_t)(r0 + ar1) * DIM + ag * 8;

    const short* bsrc = isl ? rwh : (pwh + (size_t)c0 * DIM);
    int bc[2], bg[2];
    const short* bph[2];
    const short* bpl[2];
#pragma unroll
    for (int i = 0; i < 2; ++i) {
        int u = i * 256 + tid;
        bc[i] = u >> 3; bg[i] = u & 7;
        bph[i] = bsrc + (size_t)bc[i] * DIM + bg[i] * 8;
        bpl[i] = rwl + (size_t)bc[i] * DIM + bg[i] * 8;   // only read when isl
    }

    f32x4 acc[4] = {{0.f, 0.f, 0.f, 0.f}, {0.f, 0.f, 0.f, 0.f},
                    {0.f, 0.f, 0.f, 0.f}, {0.f, 0.f, 0.f, 0.f}};

    s16x8 apre0, apre1, alpre0, alpre1;
    s16x8 bpre[2], blpre[2];
    apre0 = *(const s16x8*)aptr0;
    apre1 = *(const s16x8*)aptr1;
    if (isl) { alpre0 = *(const s16x8*)alptr0; alpre1 = *(const s16x8*)alptr1; }
#pragma unroll
    for (int i = 0; i < 2; ++i) {
        bpre[i] = *(const s16x8*)bph[i];
        if (isl) blpre[i] = *(const s16x8*)bpl[i];
    }

    for (int k0 = 0; k0 < DIM; k0 += 64) {
        *(s16x8*)&As[ar0 * LDSS + ag * 8] = apre0;
        *(s16x8*)&As[ar1 * LDSS + ag * 8] = apre1;
#pragma unroll
        for (int i = 0; i < 2; ++i)
            *(s16x8*)&Bs[bc[i] * LDSS + bg[i] * 8] = bpre[i];
        if (isl) {
            *(s16x8*)&Al[ar0 * LDSS + ag * 8] = alpre0;
            *(s16x8*)&Al[ar1 * LDSS + ag * 8] = alpre1;
#pragma unroll
            for (int i = 0; i < 2; ++i)
                *(s16x8*)&Bl[bc[i] * LDSS + bg[i] * 8] = blpre[i];
        }
        __syncthreads();

        int kn = k0 + 64;
        if (kn < DIM) {
            apre0 = *(const s16x8*)(aptr0 + kn);
            apre1 = *(const s16x8*)(aptr1 + kn);
            if (isl) {
                alpre0 = *(const s16x8*)(alptr0 + kn);
                alpre1 = *(const s16x8*)(alptr1 + kn);
            }
#pragma unroll
            for (int i = 0; i < 2; ++i) {
                bpre[i] = *(const s16x8*)(bph[i] + kn);
                if (isl) blpre[i] = *(const s16x8*)(bpl[i] + kn);
            }
        }

#pragma unroll
        for (int kk = 0; kk < 64; kk += 32) {
            int ao = (wv * 16 + fm) * LDSS + kk + q * 8;
            s16x8 a = *(const s16x8*)&As[ao];
            if (!isl) {
#pragma unroll
                for (int n = 0; n < 4; ++n) {
                    s16x8 b = *(const s16x8*)&Bs[(n * 16 + fm) * LDSS + kk + q * 8];
                    acc[n] = __builtin_amdgcn_mfma_f32_16x16x32_bf16(a, b, acc[n], 0, 0, 0);
                }
            } else {
                s16x8 al = *(const s16x8*)&Al[ao];
#pragma unroll
                for (int n = 0; n < 4; ++n) {
                    int bo = (n * 16 + fm) * LDSS + kk + q * 8;
                    s16x8 b  = *(const s16x8*)&Bs[bo];
                    s16x8 bl = *(const s16x8*)&Bl[bo];
                    acc[n] = __builtin_amdgcn_mfma_f32_16x16x32_bf16(a,  b,  acc[n], 0, 0, 0);
                    acc[n] = __builtin_amdgcn_mfma_f32_16x16x32_bf16(a,  bl, acc[n], 0, 0, 0);
                    acc[n] = __builtin_amdgcn_mfma_f32_16x16x32_bf16(al, b,  acc[n], 0, 0, 0);
                }
            }
        }
        __syncthreads();
    }

    if (!isl) {
        float bias[4];
#pragma unroll
        for (int n = 0; n < 4; ++n) bias[n] = pb[c0 + n * 16 + fm];
#pragma unroll
        for (int r = 0; r < 4; ++r) {
            int row = r0 + wv * 16 + q * 4 + r;
            float* op = out_params + (size_t)row * PARAM_DIM + c0;
#pragma unroll
            for (int n = 0; n < 4; ++n) op[n * 16 + fm] = acc[n][r] + bias[n];
        }
    } else {
        float rbv[4];
#pragma unroll
        for (int n = 0; n < 4; ++n) {
            int c = n * 16 + fm;
            rbv[n] = (c < N_TOOLS) ? rb[c] : 0.f;
        }
#pragma unroll
        for (int rr = 0; rr < 4; ++rr) {
            int row_l = wv * 16 + q * 4 + rr;
            int row = r0 + row_l;
            float v[4];
            float vmax = -INFINITY; int vcol = N_TOOLS;
#pragma unroll
            for (int n = 0; n < 4; ++n) {
                int c = n * 16 + fm;
                v[n] = acc[n][rr] + rbv[n];
                if (c < N_TOOLS && v[n] > vmax) { vmax = v[n]; vcol = c; }
            }
#pragma unroll
            for (int s = 1; s < 16; s <<= 1) {
                float om = __shfl_xor(vmax, s, 64);
                int   oc = __shfl_xor(vcol, s, 64);
                if (om > vmax || (om == vmax && oc < vcol)) { vmax = om; vcol = oc; }
            }
            float e[4]; float esum = 0.f;
#pragma unroll
            for (int n = 0; n < 4; ++n) {
                int c = n * 16 + fm;
                e[n] = (c < N_TOOLS) ? expf(v[n] - vmax) : 0.f;
                esum += e[n];
            }
#pragma unroll
            for (int s = 1; s < 16; s <<= 1) esum += __shfl_xor(esum, s, 64);
            float inv = 1.f / esum;
#pragma unroll
            for (int n = 0; n < 4; ++n) {
                int c = n * 16 + fm;
                if (c < N_TOOLS) probs[(size_t)row * N_TOOLS + c] = e[n] * inv;
            }
            if (fm == 0) {
                out_idx[row] = (float)vcol;
                idx_i[row] = vcol;
                rowcol[row_l] = vcol;
            }
        }
        __syncthreads();   // isl is block-uniform
        if (wv == 0) {
            int myc = rowcol[lane];
            int cnt = 0;
            for (int e2 = 0; e2 < N_TOOLS; ++e2) {
                unsigned long long m = __ballot(myc == e2);
                if (lane == e2) cnt = __popcll(m);
            }
            if (lane < N_TOOLS && cnt > 0) atomicAdd(&counts[lane], cnt);
        }
    }
}

// ---------------- reorder: in-block offsets scan + block-aggregated atomic placement ----------------
// Replaces plumb+reorder. cursor starts at 0; final slot = offsets(e) + cursor-bump + rank.
__global__ __launch_bounds__(256) void reorder_kernel(const int* __restrict__ idx_i,
                                                      const int* __restrict__ counts,
                                                      int* __restrict__ cursor,
                                                      int* __restrict__ order) {
    __shared__ int lcnt[N_TOOLS];
    __shared__ int loffs[64];
    __shared__ int lbase[N_TOOLS];
    int tid = threadIdx.x;
    int wv = tid >> 6;
    int lane = tid & 63;
    if (tid < N_TOOLS) lcnt[tid] = 0;
    if (wv == 1) {   // wave 1: exclusive scan of global counts (counts[50..63] zeroed by cvt)
        int c = counts[lane];
        int pre = c;
#pragma unroll
        for (int s = 1; s < 64; s <<= 1) {
            int v = __shfl_up(pre, s, 64);
            if (lane >= s) pre += v;
        }
        loffs[lane] = pre - c;
    }
    __syncthreads();
    int t = blockIdx.x * 256 + tid;
    int e = idx_i[t];
    int r = atomicAdd(&lcnt[e], 1);
    __syncthreads();
    if (tid < N_TOOLS && lcnt[tid] > 0) lbase[tid] = atomicAdd(&cursor[tid], lcnt[tid]);
    __syncthreads();
    order[loffs[e] + lbase[e] + r] = t;
}

// ---------------- adapted: grouped bf16 MFMA GEMM, in-block batch derivation ----------------
// grid (8, MAXB), block 256 (4 waves). Tile 128x64, BK=64, register-prefetch pipeline.
__global__ __launch_bounds__(256) void adapted_mfma(const short* __restrict__ xh,
                                                    const float* __restrict__ ew,
                                                    const float* __restrict__ eb,
                                                    const int* __restrict__ order,
                                                    const int* __restrict__ counts,
                                                    float* __restrict__ out) {
    __shared__ short As[TM * LDSS];
    __shared__ short Bs[64 * LDSS];
    __shared__ int toks[TM];
    __shared__ int cshare[64];

    int b = blockIdx.y;
    int c0 = blockIdx.x * 64;
    int tid = threadIdx.x;

    if (tid < 64) cshare[tid] = (tid < N_TOOLS) ? counts[tid] : 0;
    __syncthreads();
    // derive (expert, m0, global offset) for batch b from counts (proven in r5 mega phase 4)
    int e = -1, m0 = 0, off = 0, ce = 0;
    int accb = 0, acco = 0;
    for (int i = 0; i < N_TOOLS; ++i) {
        int c = cshare[i];
        int nb = (c + TM - 1) >> 7;
        if (e < 0 && b < accb + nb) { e = i; m0 = (b - accb) * TM; off = acco; ce = c; }
        accb += nb; acco += c;
    }
    if (e < 0) return;   // b >= nb_total (block-uniform)
    int start = off + m0;
    int len = ce - m0;
    if (len > TM) len = TM;

    if (tid < TM) toks[tid] = (tid < len) ? order[start + tid] : -1;
    __syncthreads();

    int wv = tid >> 6;
    int lane = tid & 63;
    int fm = lane & 15;
    int q = lane >> 4;

    const float* We = ew + (size_t)e * DIM * DIM;

    int ag = tid & 7;
    int ar[4]; const short* aptr[4];
#pragma unroll
    for (int i = 0; i < 4; ++i) {
        ar[i] = i * 32 + (tid >> 3);
        int tk = toks[ar[i]];
        aptr[i] = (tk >= 0) ? xh + (size_t)tk * DIM + ag * 8 : nullptr;
    }
    int bc[4], bg[4];
    const float* bptr[4];
#pragma unroll
    for (int i = 0; i < 4; ++i) {
        int u = i * 256 + tid;
        bc[i] = u >> 4; bg[i] = u & 15;
        bptr[i] = We + (size_t)(c0 + bc[i]) * DIM + bg[i] * 4;
    }

    f32x4 acc[8] = {{0.f,0.f,0.f,0.f},{0.f,0.f,0.f,0.f},{0.f,0.f,0.f,0.f},{0.f,0.f,0.f,0.f},
                    {0.f,0.f,0.f,0.f},{0.f,0.f,0.f,0.f},{0.f,0.f,0.f,0.f},{0.f,0.f,0.f,0.f}};

    const s16x8 z8 = {0, 0, 0, 0, 0, 0, 0, 0};
    s16x8 apre[4];
    float4 bpre[4];
#pragma unroll
    for (int i = 0; i < 4; ++i) apre[i] = aptr[i] ? *(const s16x8*)aptr[i] : z8;
#pragma unroll
    for (int i = 0; i < 4; ++i) bpre[i] = *(const float4*)bptr[i];

    for (int k0 = 0; k0 < DIM; k0 += 64) {
#pragma unroll
        for (int i = 0; i < 4; ++i)
            *(s16x8*)&As[ar[i] * LDSS + ag * 8] = apre[i];
#pragma unroll
        for (int i = 0; i < 4; ++i) {
            float4 v = bpre[i];
            *(s16x4*)&Bs[bc[i] * LDSS + bg[i] * 4] = pk4(v.x, v.y, v.z, v.w);
        }
        __syncthreads();

        int kn = k0 + 64;
        if (kn < DIM) {
#pragma unroll
            for (int i = 0; i < 4; ++i) apre[i] = aptr[i] ? *(const s16x8*)(aptr[i] + kn) : z8;
#pragma unroll
            for (int i = 0; i < 4; ++i) bpre[i] = *(const float4*)(bptr[i] + kn);
        }

#pragma unroll
        for (int kk = 0; kk < 64; kk += 32) {
            s16x8 a0 = *(const s16x8*)&As[(wv * 32 + fm) * LDSS + kk + q * 8];
            s16x8 a1 = *(const s16x8*)&As[(wv * 32 + 16 + fm) * LDSS + kk + q * 8];
#pragma unroll
            for (int n = 0; n < 4; ++n) {
                s16x8 bf = *(const s16x8*)&Bs[(n * 16 + fm) * LDSS + kk + q * 8];
                acc[n]     = __builtin_amdgcn_mfma_f32_16x16x32_bf16(a0, bf, acc[n],     0, 0, 0);
                acc[4 + n] = __builtin_amdgcn_mfma_f32_16x16x32_bf16(a1, bf, acc[4 + n], 0, 0, 0);
            }
        }
        __syncthreads();
    }

    float bias[4];
#pragma unroll
    for (int n = 0; n < 4; ++n) bias[n] = eb[(size_t)e * DIM + c0 + n * 16 + fm];

#pragma unroll
    for (int m = 0; m < 2; ++m) {
#pragma unroll
        for (int r = 0; r < 4; ++r) {
            int row = wv * 32 + m * 16 + q * 4 + r;
            int tok = toks[row];
            if (tok < 0) continue;
            float* op = out + (size_t)tok * DIM + c0;
#pragma unroll
            for (int n = 0; n < 4; ++n) op[n * 16 + fm] = acc[m * 4 + n][r] + bias[n];
        }
    }
}

extern "C" void kernel_launch(void* const* d_in, const int* in_sizes, int n_in,
                              void* d_out, int out_size, void* d_ws, size_t ws_size,
                              hipStream_t stream) {
    const float* x        = (const float*)d_in[0];
    const float* router_w = (const float*)d_in[1];
    const float* router_b = (const float*)d_in[2];
    const float* expert_w = (const float*)d_in[3];
    const float* expert_b = (const float*)d_in[4];
    const float* param_w  = (const float*)d_in[5];
    const float* param_b  = (const float*)d_in[6];

    float* out = (float*)d_out;
    float* out_idx     = out;                                  // 8192
    float* out_probs   = out + N_TOKENS;                       // 409600
    float* out_adapted = out + N_TOKENS + N_TOKENS * N_TOOLS;  // 4194304
    float* out_params  = out_adapted + (size_t)N_TOKENS * DIM; // 2097152

    int* ws = (int*)d_ws;
    int* ws_idx     = ws + WS_IDX;
    int* ws_counts  = ws + WS_COUNTS;
    int* ws_cursor  = ws + WS_CURSOR;
    int* ws_order   = ws + WS_ORDER;
    short* ws_pwh   = (short*)(ws + WS_PWH);
    short* ws_rwh   = (short*)(ws + WS_RWH);
    short* ws_rwl   = (short*)(ws + WS_RWL);
    short* ws_xh    = (short*)(ws + WS_XH);
    short* ws_xl    = (short*)(ws + WS_XL);

    cvt_kernel<<<CVT_GRID, 256, 0, stream>>>(x, param_w, router_w,
                                             ws_xh, ws_xl, ws_pwh, ws_rwh, ws_rwl,
                                             ws_counts, ws_cursor);

    head_mfma<<<dim3(5, N_ROWBLK), 256, 0, stream>>>(ws_xh, ws_xl, ws_pwh, param_b,
                                                     ws_rwh, ws_rwl, router_b,
                                                     out_params, out_probs,
                                                     out_idx, ws_idx, ws_counts);

    reorder_kernel<<<N_TOKENS / 256, 256, 0, stream>>>(ws_idx, ws_counts, ws_cursor, ws_order);

    adapted_mfma<<<dim3(8, MAXB), 256, 0, stream>>>(ws_xh, expert_w, expert_b,
                                                    ws_order, ws_counts, out_adapted);
}